// Round 8
// baseline (1606.842 us; speedup 1.0000x reference)
//
#include <hip/hip_runtime.h>

#define TT 2048
#define II 64
#define HH 256
#define MPB 8        // batches per block -> 8 blocks
#define HSTR 296     // hbuf row stride in halfs (592 B): A-reads <=2-way conflicts
#define PSTR 9       // part[] stride in floats: conflict-free post-loop reads

typedef __fp16 f16x2 __attribute__((ext_vector_type(2)));
typedef __fp16 f16x8 __attribute__((ext_vector_type(8)));
typedef float  f32x4 __attribute__((ext_vector_type(4)));

#define MFMA(a, b, c) __builtin_amdgcn_mfma_f32_16x16x32_f16((a), (b), (c), 0, 0, 0)

// pack 8 fp32 -> f16x8 A/B fragment
__device__ __forceinline__ f16x8 pack8(float4 a, float4 b) {
    int4 iv;
    iv.x = __builtin_bit_cast(int, __builtin_amdgcn_cvt_pkrtz(a.x, a.y));
    iv.y = __builtin_bit_cast(int, __builtin_amdgcn_cvt_pkrtz(a.z, a.w));
    iv.z = __builtin_bit_cast(int, __builtin_amdgcn_cvt_pkrtz(b.x, b.y));
    iv.w = __builtin_bit_cast(int, __builtin_amdgcn_cvt_pkrtz(b.z, b.w));
    return __builtin_bit_cast(f16x8, iv);
}

// tanh(x) = 1 - 2/(e^{2x}+1)
__device__ __forceinline__ float ftanh(float x) {
    float e = __expf(2.0f * x);
    return 1.0f - 2.0f * __builtin_amdgcn_rcpf(e + 1.0f);
}

// 512 thr = 8 waves (2/SIMD). Per step: one [16x320]x[320x256] MFMA matmul for
// 8 real batches (rows 8-15 of M are zero padding). R3-R7 lesson: per-lane
// GEMV + cross-lane reduces is issue/latency-bound at ~1500 cyc/step; MFMA
// moves the dot work to the matrix pipe and kills the reduce trees.
__launch_bounds__(512, 2)
__global__ void rnn_mfma(const float* __restrict__ x,
                         const float* __restrict__ W_ih,
                         const float* __restrict__ W_hh,
                         const float* __restrict__ b_ih,
                         const float* __restrict__ b_hh,
                         const float* __restrict__ W_fc,
                         const float* __restrict__ b_fc,
                         float* __restrict__ out) {
    // h (fp16) double-buffered, batch-major [m][k=row], row stride HSTR halfs.
    __shared__ __align__(16) __fp16 hbuf[2][MPB * HSTR];
    __shared__ float part[(TT + 1) * PSTR];  // per-step head results

    const int tid  = threadIdx.x;
    const int b0   = blockIdx.x;        // batch group: batches b0*8 .. b0*8+7
    const int lane = tid & 63;
    const int w    = tid >> 6;          // wave 0..7 -> rows [w*32, w*32+32)
    const int nl   = lane & 15;         // tile col n / A-operand m (batch)
    const int g    = lane >> 4;         // 0..3: k-subgroup / C batch-group

    // ---- B-fragments (weights), pinned in VGPRs ----
    // B[k][n]: lane holds n=nl, k = kb*32 + g*8 + j. kb 0-7: W_hh^T; 8-9: W_ih^T.
    f16x8 wb0[10], wb1[10];
    const int r0 = w * 32 + nl, r1 = r0 + 16;
#pragma unroll
    for (int kb = 0; kb < 8; ++kb) {
        const float4* p0 = (const float4*)(W_hh + r0 * HH + kb * 32 + g * 8);
        wb0[kb] = pack8(p0[0], p0[1]);
        const float4* p1 = (const float4*)(W_hh + r1 * HH + kb * 32 + g * 8);
        wb1[kb] = pack8(p1[0], p1[1]);
    }
#pragma unroll
    for (int kb = 8; kb < 10; ++kb) {
        const float4* p0 = (const float4*)(W_ih + r0 * II + (kb - 8) * 32 + g * 8);
        wb0[kb] = pack8(p0[0], p0[1]);
        const float4* p1 = (const float4*)(W_ih + r1 * II + (kb - 8) * 32 + g * 8);
        wb1[kb] = pack8(p1[0], p1[1]);
    }
#pragma unroll
    for (int kb = 0; kb < 10; ++kb)
        asm volatile("" : "+v"(wb0[kb]), "+v"(wb1[kb]));  // R6 lesson: forbid sinking

    // head B-fragment (wave 0): B[k][0] = W_fc[k], other cols zero
    const f16x8 z8 = {0, 0, 0, 0, 0, 0, 0, 0};
    f16x8 whd[8];
#pragma unroll
    for (int kb = 0; kb < 8; ++kb) whd[kb] = z8;
    if (w == 0) {
        if (nl == 0) {
#pragma unroll
            for (int kb = 0; kb < 8; ++kb) {
                const float4* pf = (const float4*)(W_fc + kb * 32 + g * 8);
                whd[kb] = pack8(pf[0], pf[1]);
            }
        }
#pragma unroll
        for (int kb = 0; kb < 8; ++kb) asm volatile("" : "+v"(whd[kb]));
    }

    const float bias0 = b_ih[r0] + b_hh[r0];
    const float bias1 = b_ih[r1] + b_hh[r1];
    const float bfc   = b_fc[0];

    for (int idx = tid; idx < 2 * MPB * HSTR; idx += 512)
        ((__fp16*)hbuf)[idx] = (__fp16)0.0f;
    __syncthreads();

    // ---- A-fragments: A[m=nl][k]; lanes nl>=8 stay zero (M padding) ----
    f16x8 af[10];
#pragma unroll
    for (int kb = 0; kb < 10; ++kb) af[kb] = z8;

    const float* xrow = x + ((size_t)(b0 * MPB + (nl & 7)) * TT) * II + g * 8;
    float4 xa0, xa1, xb0, xb1;
    if (nl < 8) {
        const float4* xp = (const float4*)xrow;
        xa0 = xp[0]; xa1 = xp[1];
        const float4* xq = (const float4*)(xrow + 32);
        xb0 = xq[0]; xb1 = xq[1];
    }

    int p = 0;
    for (int i = 0; i < TT; ++i) {
        if (nl < 8) {
            // x k-blocks for this step; prefetch next step's x
            af[8] = pack8(xa0, xa1);
            af[9] = pack8(xb0, xb1);
            const float* xn = xrow + (size_t)((i + 1 < TT) ? (i + 1) : i) * II;
            const float4* xp = (const float4*)xn;
            xa0 = xp[0]; xa1 = xp[1];
            const float4* xq = (const float4*)(xn + 32);
            xb0 = xq[0]; xb1 = xq[1];
            // h A-frags from LDS
            const __fp16* hp = &hbuf[p][nl * HSTR + g * 8];
#pragma unroll
            for (int kb = 0; kb < 8; ++kb)
                af[kb] = *(const f16x8*)(hp + kb * 32);
        }

        // ---- main MFMA: 2 N-tiles x 10 k-blocks ----
        f32x4 c0 = {bias0, bias0, bias0, bias0};
        f32x4 c1 = {bias1, bias1, bias1, bias1};
#pragma unroll
        for (int kb = 0; kb < 10; ++kb) {
            c0 = MFMA(af[kb], wb0[kb], c0);
            c1 = MFMA(af[kb], wb1[kb], c1);
        }

        // ---- head: out[i-1] = h_i . W_fc via one MFMA chain (wave 0) ----
        if (w == 0) {
            f32x4 ch = {0.0f, 0.0f, 0.0f, 0.0f};
#pragma unroll
            for (int kb = 0; kb < 8; ++kb) ch = MFMA(af[kb], whd[kb], ch);
            if (nl == 0 && g < 2) {
                float* pp = &part[i * PSTR + g * 4];
                pp[0] = ch[0]; pp[1] = ch[1]; pp[2] = ch[2]; pp[3] = ch[3];
            }
        }

        // ---- tanh + h write (C: batch=(g*4+r), col=nl -> batches<8: g<2) ----
        const int pn = p ^ 1;
        if (g < 2) {
            __fp16* hw = &hbuf[pn][w * 32 + nl];
#pragma unroll
            for (int r = 0; r < 4; ++r) {
                hw[(g * 4 + r) * HSTR]      = (__fp16)ftanh(c0[r]);
                hw[(g * 4 + r) * HSTR + 16] = (__fp16)ftanh(c1[r]);
            }
        }

        __syncthreads();  // h_{i+1} visible; ONE barrier per step
        p = pn;
    }

    // ---- epilogue: out[TT-1] needs h_TT . W_fc ----
    if (w == 0) {
        f16x8 ef[8];
#pragma unroll
        for (int kb = 0; kb < 8; ++kb) ef[kb] = z8;
        if (nl < 8) {
            const __fp16* hp = &hbuf[p][nl * HSTR + g * 8];
#pragma unroll
            for (int kb = 0; kb < 8; ++kb)
                ef[kb] = *(const f16x8*)(hp + kb * 32);
        }
        f32x4 ch = {0.0f, 0.0f, 0.0f, 0.0f};
#pragma unroll
        for (int kb = 0; kb < 8; ++kb) ch = MFMA(ef[kb], whd[kb], ch);
        if (nl == 0 && g < 2) {
            float* pp = &part[TT * PSTR + g * 4];
            pp[0] = ch[0]; pp[1] = ch[1]; pp[2] = ch[2]; pp[3] = ch[3];
        }
    }
    __syncthreads();

    // ---- write out: out[b][t] = part[t+1][b] + bfc ----
    for (int idx = tid; idx < MPB * TT; idx += 512) {
        const int bi = idx >> 11;          // batch within group
        const int t  = idx & (TT - 1);
        out[((size_t)(b0 * MPB + bi)) * TT + t] = part[(t + 1) * PSTR + bi] + bfc;
    }
}

extern "C" void kernel_launch(void* const* d_in, const int* in_sizes, int n_in,
                              void* d_out, int out_size, void* d_ws, size_t ws_size,
                              hipStream_t stream) {
    const float* x    = (const float*)d_in[0];
    const float* W_ih = (const float*)d_in[1];
    const float* W_hh = (const float*)d_in[2];
    const float* b_ih = (const float*)d_in[3];
    const float* b_hh = (const float*)d_in[4];
    const float* W_fc = (const float*)d_in[5];
    const float* b_fc = (const float*)d_in[6];
    float* out = (float*)d_out;

    rnn_mfma<<<64 / MPB, 512, 0, stream>>>(x, W_ih, W_hh, b_ih, b_hh, W_fc, b_fc, out);
}